// Round 2
// baseline (466.422 us; speedup 1.0000x reference)
//
#include <hip/hip_runtime.h>
#include <float.h>

#define BLK 256
#define CHUNKS 4

// Pass 1: transform each target point p -> (-px, -py, -pz, 0.5*||p||^2)
// so the main loop computes 0.5*||y||^2 - x.y with mul+2fma (+add +min).
__global__ __launch_bounds__(BLK) void transform_kernel(
    const float* __restrict__ xyz1, const float* __restrict__ xyz2,
    float4* __restrict__ t1, float4* __restrict__ t2, int n1, int n2)
{
    const int i = blockIdx.x * BLK + threadIdx.x;
    if (i < n1) {
        const float x = xyz1[3*(size_t)i], y = xyz1[3*(size_t)i+1], z = xyz1[3*(size_t)i+2];
        t1[i] = make_float4(-x, -y, -z, 0.5f * fmaf(x, x, fmaf(y, y, z * z)));
    }
    if (i < n2) {
        const float x = xyz2[3*(size_t)i], y = xyz2[3*(size_t)i+1], z = xyz2[3*(size_t)i+2];
        t2[i] = make_float4(-x, -y, -z, 0.5f * fmaf(x, x, fmaf(y, y, z * z)));
    }
}

// Pass 2: each block handles (dir, batch, query-tile, target-chunk).
// Target loads are block-uniform -> scalar (SMEM) pipe, zero VALU cost.
__global__ __launch_bounds__(BLK) void chamfer_main(
    const float* __restrict__ xyz1, const float* __restrict__ xyz2,
    const float4* __restrict__ t1, const float4* __restrict__ t2,
    float* __restrict__ partial, int B, int N, int M, int outn)
{
    const int z     = blockIdx.z;
    const int dir   = z / CHUNKS;
    const int chunk = z % CHUNKS;
    const int b     = blockIdx.y;

    const float*  Q  = (dir == 0) ? xyz1 : xyz2;
    const float4* T  = (dir == 0) ? t2   : t1;
    const int nQ = (dir == 0) ? N : M;
    const int nT = (dir == 0) ? M : N;

    const int i = blockIdx.x * BLK + threadIdx.x;

    float x0 = 0.f, x1 = 0.f, x2v = 0.f;
    if (i < nQ) {
        const float* q = Q + ((size_t)b * nQ + i) * 3;
        x0 = q[0]; x1 = q[1]; x2v = q[2];
    }

    const float4* __restrict__ Tb = T + (size_t)b * nT;
    const int span = nT / CHUNKS;
    const int j0 = chunk * span;
    const int j1 = (chunk == CHUNKS - 1) ? nT : j0 + span;

    // f(p) = x.(-p.xyz) + 0.5||p||^2 ; dist = 2*min f + ||x||^2
    // mul + fma + fma (<=1 SGPR operand each) + add + min = 5 VALU ops/pair.
    float b0 = FLT_MAX, b1 = FLT_MAX, b2 = FLT_MAX, b3 = FLT_MAX;

    int j = j0;
    for (; j + 8 <= j1; j += 8) {
        const float4 p0 = Tb[j + 0];
        const float4 p1 = Tb[j + 1];
        const float4 p2 = Tb[j + 2];
        const float4 p3 = Tb[j + 3];
        const float4 p4 = Tb[j + 4];
        const float4 p5 = Tb[j + 5];
        const float4 p6 = Tb[j + 6];
        const float4 p7 = Tb[j + 7];
        b0 = fminf(b0, fmaf(x0, p0.x, fmaf(x1, p0.y, x2v * p0.z)) + p0.w);
        b1 = fminf(b1, fmaf(x0, p1.x, fmaf(x1, p1.y, x2v * p1.z)) + p1.w);
        b2 = fminf(b2, fmaf(x0, p2.x, fmaf(x1, p2.y, x2v * p2.z)) + p2.w);
        b3 = fminf(b3, fmaf(x0, p3.x, fmaf(x1, p3.y, x2v * p3.z)) + p3.w);
        b0 = fminf(b0, fmaf(x0, p4.x, fmaf(x1, p4.y, x2v * p4.z)) + p4.w);
        b1 = fminf(b1, fmaf(x0, p5.x, fmaf(x1, p5.y, x2v * p5.z)) + p5.w);
        b2 = fminf(b2, fmaf(x0, p6.x, fmaf(x1, p6.y, x2v * p6.z)) + p6.w);
        b3 = fminf(b3, fmaf(x0, p7.x, fmaf(x1, p7.y, x2v * p7.z)) + p7.w);
    }
    for (; j < j1; ++j) {  // safety tail (not hit for 8192/4)
        const float4 p = Tb[j];
        b0 = fminf(b0, fmaf(x0, p.x, fmaf(x1, p.y, x2v * p.z)) + p.w);
    }

    if (i < nQ) {
        const float m  = fminf(fminf(b0, b1), fminf(b2, b3));
        const float xx = fmaf(x0, x0, fmaf(x1, x1, x2v * x2v));
        const float dist = fmaf(2.f, m, xx);
        const size_t off = (dir == 0) ? ((size_t)b * N + i)
                                      : ((size_t)B * N + (size_t)b * M + i);
        partial[(size_t)chunk * outn + off] = dist;
    }
}

// Pass 3: min over chunks.
__global__ __launch_bounds__(BLK) void reduce_kernel(
    const float* __restrict__ partial, float* __restrict__ out, int outn)
{
    const int k = blockIdx.x * BLK + threadIdx.x;
    if (k < outn) {
        float m = partial[k];
#pragma unroll
        for (int c = 1; c < CHUNKS; ++c)
            m = fminf(m, partial[(size_t)c * outn + k]);
        out[k] = m;
    }
}

// Round-1 fallback (used only if ws_size is too small).
__global__ __launch_bounds__(BLK) void chamfer_fallback(
    const float* __restrict__ xyz1, const float* __restrict__ xyz2,
    float* __restrict__ out, int B, int N, int M)
{
    const int dir = blockIdx.z;
    const int b   = blockIdx.y;
    const float* Q = (dir == 0) ? xyz1 : xyz2;
    const float* T = (dir == 0) ? xyz2 : xyz1;
    const int nQ = (dir == 0) ? N : M;
    const int nT = (dir == 0) ? M : N;
    const int i = blockIdx.x * BLK + threadIdx.x;

    float x0 = 0.f, x1 = 0.f, x2 = 0.f;
    if (i < nQ) {
        const float* q = Q + ((size_t)b * nQ + i) * 3;
        x0 = q[0]; x1 = q[1]; x2 = q[2];
    }
    auto dist = [&](float y0, float y1, float y2) -> float {
        float t0 = y0 - x0, t1 = y1 - x1, t2 = y2 - x2;
        return fmaf(t0, t0, fmaf(t1, t1, t2 * t2));
    };
    float best = FLT_MAX;
    for (int j = 0; j < nT; ++j) {
        const float* t = T + ((size_t)b * nT + j) * 3;
        best = fminf(best, dist(t[0], t[1], t[2]));
    }
    if (i < nQ) {
        const size_t off = (dir == 0) ? ((size_t)b * N + i)
                                      : ((size_t)B * N + (size_t)b * M + i);
        out[off] = best;
    }
}

extern "C" void kernel_launch(void* const* d_in, const int* in_sizes, int n_in,
                              void* d_out, int out_size, void* d_ws, size_t ws_size,
                              hipStream_t stream) {
    const float* xyz1 = (const float*)d_in[0];
    const float* xyz2 = (const float*)d_in[1];
    float* out = (float*)d_out;

    const int B = 8, N = 8192, M = 8192;
    const int n1 = B * N, n2 = B * M;
    const int outn = B * (N + M);

    const size_t t1_bytes = (size_t)n1 * sizeof(float4);
    const size_t t2_bytes = (size_t)n2 * sizeof(float4);
    const size_t part_bytes = (size_t)CHUNKS * outn * sizeof(float);
    const size_t need = t1_bytes + t2_bytes + part_bytes;

    if (ws_size >= need) {
        float4* t1 = (float4*)d_ws;
        float4* t2 = (float4*)((char*)d_ws + t1_bytes);
        float* partial = (float*)((char*)d_ws + t1_bytes + t2_bytes);

        const int nmax_pts = (n1 > n2) ? n1 : n2;
        transform_kernel<<<(nmax_pts + BLK - 1) / BLK, BLK, 0, stream>>>(
            xyz1, xyz2, t1, t2, n1, n2);

        const int nmax = (N > M) ? N : M;
        dim3 grid((unsigned)((nmax + BLK - 1) / BLK), (unsigned)B, 2 * CHUNKS);
        chamfer_main<<<grid, dim3(BLK, 1, 1), 0, stream>>>(
            xyz1, xyz2, t1, t2, partial, B, N, M, outn);

        reduce_kernel<<<(outn + BLK - 1) / BLK, BLK, 0, stream>>>(partial, out, outn);
    } else {
        const int nmax = (N > M) ? N : M;
        dim3 grid((unsigned)((nmax + BLK - 1) / BLK), (unsigned)B, 2);
        chamfer_fallback<<<grid, dim3(BLK, 1, 1), 0, stream>>>(xyz1, xyz2, out, B, N, M);
    }
}

// Round 4
// 131.154 us; speedup vs baseline: 3.5563x; 3.5563x over previous
//
#include <hip/hip_runtime.h>
#include <float.h>

#define BLK 256
#define QPT 8   // query points per thread

// Pass 1: transform each target point p -> (-px, -py, -pz, 0.5*||p||^2).
// Inner loop then computes f = 0.5||p||^2 - q.p with a 3-FMA chain;
// dist = 2*min f + ||q||^2.
__global__ __launch_bounds__(BLK) void transform_kernel(
    const float* __restrict__ xyz1, const float* __restrict__ xyz2,
    float4* __restrict__ t1, float4* __restrict__ t2, int n1, int n2)
{
    const int i = blockIdx.x * BLK + threadIdx.x;
    if (i < n1) {
        const float x = xyz1[3*(size_t)i], y = xyz1[3*(size_t)i+1], z = xyz1[3*(size_t)i+2];
        t1[i] = make_float4(-x, -y, -z, 0.5f * fmaf(x, x, fmaf(y, y, z * z)));
    }
    if (i < n2) {
        const float x = xyz2[3*(size_t)i], y = xyz2[3*(size_t)i+1], z = xyz2[3*(size_t)i+2];
        t2[i] = make_float4(-x, -y, -z, 0.5f * fmaf(x, x, fmaf(y, y, z * z)));
    }
}

// Pass 2: register-tiled main loop. Each thread owns QPT query points;
// one uniform float4 target load is reused for QPT pairs (VALU:VMEM = 32:1).
__global__ __launch_bounds__(BLK) void chamfer_main(
    const float* __restrict__ xyz1, const float* __restrict__ xyz2,
    const float4* __restrict__ t1, const float4* __restrict__ t2,
    float* __restrict__ partial, int B, int N, int M, int outn, int lc /*log2 chunks*/)
{
    const int chunks = 1 << lc;
    const int z     = blockIdx.z;
    const int dir   = z >> lc;
    const int chunk = z & (chunks - 1);
    const int b     = blockIdx.y;

    const float*  Q = (dir == 0) ? xyz1 : xyz2;
    const float4* T = (dir == 0) ? t2   : t1;
    const int nQ = (dir == 0) ? N : M;
    const int nT = (dir == 0) ? M : N;

    const int qbase = blockIdx.x * (BLK * QPT) + threadIdx.x;

    float qx[QPT], qy[QPT], qz[QPT];
#pragma unroll
    for (int k = 0; k < QPT; ++k) {
        const int idx = qbase + k * BLK;
        if (idx < nQ) {
            const float* q = Q + ((size_t)b * nQ + idx) * 3;
            qx[k] = q[0]; qy[k] = q[1]; qz[k] = q[2];
        } else {
            qx[k] = 0.f; qy[k] = 0.f; qz[k] = 0.f;
        }
    }

    float acc[QPT];
#pragma unroll
    for (int k = 0; k < QPT; ++k) acc[k] = FLT_MAX;

    const float4* __restrict__ Tb = T + (size_t)b * nT;
    const int span = nT >> lc;          // nT = 8192 divisible by chunks (pow2)
    const int j0 = chunk * span;
    const int j1 = j0 + span;

    int j = j0;
    for (; j + 4 <= j1; j += 4) {
        const float4 p0 = Tb[j + 0];
        const float4 p1 = Tb[j + 1];
        const float4 p2 = Tb[j + 2];
        const float4 p3 = Tb[j + 3];
#pragma unroll
        for (int k = 0; k < QPT; ++k)
            acc[k] = fminf(acc[k], fmaf(qx[k], p0.x, fmaf(qy[k], p0.y, fmaf(qz[k], p0.z, p0.w))));
#pragma unroll
        for (int k = 0; k < QPT; ++k)
            acc[k] = fminf(acc[k], fmaf(qx[k], p1.x, fmaf(qy[k], p1.y, fmaf(qz[k], p1.z, p1.w))));
#pragma unroll
        for (int k = 0; k < QPT; ++k)
            acc[k] = fminf(acc[k], fmaf(qx[k], p2.x, fmaf(qy[k], p2.y, fmaf(qz[k], p2.z, p2.w))));
#pragma unroll
        for (int k = 0; k < QPT; ++k)
            acc[k] = fminf(acc[k], fmaf(qx[k], p3.x, fmaf(qy[k], p3.y, fmaf(qz[k], p3.z, p3.w))));
    }
    for (; j < j1; ++j) {   // safety tail (not hit: span multiple of 4)
        const float4 p = Tb[j];
#pragma unroll
        for (int k = 0; k < QPT; ++k)
            acc[k] = fminf(acc[k], fmaf(qx[k], p.x, fmaf(qy[k], p.y, fmaf(qz[k], p.z, p.w))));
    }

#pragma unroll
    for (int k = 0; k < QPT; ++k) {
        const int idx = qbase + k * BLK;
        if (idx < nQ) {
            const float qq = fmaf(qx[k], qx[k], fmaf(qy[k], qy[k], qz[k] * qz[k]));
            const float dist = fmaf(2.f, acc[k], qq);
            const size_t off = (dir == 0) ? ((size_t)b * N + idx)
                                          : ((size_t)B * N + (size_t)b * M + idx);
            partial[(size_t)chunk * outn + off] = dist;
        }
    }
}

// Pass 3: min over chunks.
__global__ __launch_bounds__(BLK) void reduce_kernel(
    const float* __restrict__ partial, float* __restrict__ out, int outn, int chunks)
{
    const int k = blockIdx.x * BLK + threadIdx.x;
    if (k < outn) {
        float m = partial[k];
        for (int c = 1; c < chunks; ++c)
            m = fminf(m, partial[(size_t)c * outn + k]);
        out[k] = m;
    }
}

// Round-1 style fallback (only if ws_size is too small).
__global__ __launch_bounds__(BLK) void chamfer_fallback(
    const float* __restrict__ xyz1, const float* __restrict__ xyz2,
    float* __restrict__ out, int B, int N, int M)
{
    const int dir = blockIdx.z;
    const int b   = blockIdx.y;
    const float* Q = (dir == 0) ? xyz1 : xyz2;
    const float* T = (dir == 0) ? xyz2 : xyz1;
    const int nQ = (dir == 0) ? N : M;
    const int nT = (dir == 0) ? M : N;
    const int i = blockIdx.x * BLK + threadIdx.x;

    float x0 = 0.f, x1 = 0.f, x2 = 0.f;
    if (i < nQ) {
        const float* q = Q + ((size_t)b * nQ + i) * 3;
        x0 = q[0]; x1 = q[1]; x2 = q[2];
    }
    float best = FLT_MAX;
    for (int jj = 0; jj < nT; ++jj) {
        const float* t = T + ((size_t)b * nT + jj) * 3;
        float t0 = t[0] - x0, t1 = t[1] - x1, t2 = t[2] - x2;
        best = fminf(best, fmaf(t0, t0, fmaf(t1, t1, t2 * t2)));
    }
    if (i < nQ) {
        const size_t off = (dir == 0) ? ((size_t)b * N + i)
                                      : ((size_t)B * N + (size_t)b * M + i);
        out[off] = best;
    }
}

extern "C" void kernel_launch(void* const* d_in, const int* in_sizes, int n_in,
                              void* d_out, int out_size, void* d_ws, size_t ws_size,
                              hipStream_t stream) {
    const float* xyz1 = (const float*)d_in[0];
    const float* xyz2 = (const float*)d_in[1];
    float* out = (float*)d_out;

    const int B = 8, N = 8192, M = 8192;
    const int n1 = B * N, n2 = B * M;
    const int outn = B * (N + M);

    const size_t t1_bytes = (size_t)n1 * sizeof(float4);
    const size_t t2_bytes = (size_t)n2 * sizeof(float4);

    // Pick the largest power-of-two chunk count whose partial buffer fits ws.
    int lc = -1;
    for (int try_lc = 5; try_lc >= 0; --try_lc) {   // chunks = 32..1
        const size_t part = ((size_t)1 << try_lc) * (size_t)outn * sizeof(float);
        if (t1_bytes + t2_bytes + part <= ws_size) { lc = try_lc; break; }
    }

    if (lc >= 0) {
        const int chunks = 1 << lc;
        float4* t1 = (float4*)d_ws;
        float4* t2 = (float4*)((char*)d_ws + t1_bytes);
        float* partial = (float*)((char*)d_ws + t1_bytes + t2_bytes);

        const int nmax_pts = (n1 > n2) ? n1 : n2;
        transform_kernel<<<(nmax_pts + BLK - 1) / BLK, BLK, 0, stream>>>(
            xyz1, xyz2, t1, t2, n1, n2);

        const int nmax = (N > M) ? N : M;
        dim3 grid((unsigned)((nmax + BLK * QPT - 1) / (BLK * QPT)), (unsigned)B,
                  (unsigned)(2 * chunks));
        chamfer_main<<<grid, dim3(BLK, 1, 1), 0, stream>>>(
            xyz1, xyz2, t1, t2, partial, B, N, M, outn, lc);

        reduce_kernel<<<(outn + BLK - 1) / BLK, BLK, 0, stream>>>(partial, out, outn, chunks);
    } else {
        const int nmax = (N > M) ? N : M;
        dim3 grid((unsigned)((nmax + BLK - 1) / BLK), (unsigned)B, 2);
        chamfer_fallback<<<grid, dim3(BLK, 1, 1), 0, stream>>>(xyz1, xyz2, out, B, N, M);
    }
}

// Round 5
// 122.718 us; speedup vs baseline: 3.8008x; 1.0687x over previous
//
#include <hip/hip_runtime.h>
#include <float.h>

#define BLK 256
#define QPT 8   // query points per thread

typedef float f32x16 __attribute__((ext_vector_type(16)));

// Pass 1: transform each target point p -> (-px, -py, -pz, 0.5*||p||^2).
// Main loop computes f = 0.5||p||^2 - q.p (3-FMA chain); dist = 2*min f + ||q||^2.
__global__ __launch_bounds__(BLK) void transform_kernel(
    const float* __restrict__ xyz1, const float* __restrict__ xyz2,
    float4* __restrict__ t1, float4* __restrict__ t2, int n1, int n2)
{
    const int i = blockIdx.x * BLK + threadIdx.x;
    if (i < n1) {
        const float x = xyz1[3*(size_t)i], y = xyz1[3*(size_t)i+1], z = xyz1[3*(size_t)i+2];
        t1[i] = make_float4(-x, -y, -z, 0.5f * fmaf(x, x, fmaf(y, y, z * z)));
    }
    if (i < n2) {
        const float x = xyz2[3*(size_t)i], y = xyz2[3*(size_t)i+1], z = xyz2[3*(size_t)i+2];
        t2[i] = make_float4(-x, -y, -z, 0.5f * fmaf(x, x, fmaf(y, y, z * z)));
    }
}

// Pass 2: targets fetched via SCALAR loads (s_load_dwordx16) into SGPRs —
// wave-uniform data never touches the vector L1 data-return path.
// Per 8 targets: 2 x s_load_dwordx16 (128 B); per pair: 3 FMA + 0.5 min3.
__global__ __launch_bounds__(BLK) void chamfer_main(
    const float* __restrict__ xyz1, const float* __restrict__ xyz2,
    const float4* __restrict__ t1, const float4* __restrict__ t2,
    float* __restrict__ partial, int B, int N, int M, int outn, int lc)
{
    const int chunks = 1 << lc;
    const int z     = blockIdx.z;
    const int dir   = z >> lc;
    const int chunk = z & (chunks - 1);
    const int b     = blockIdx.y;

    const float*  Q = (dir == 0) ? xyz1 : xyz2;
    const float4* T = (dir == 0) ? t2   : t1;
    const int nQ = (dir == 0) ? N : M;
    const int nT = (dir == 0) ? M : N;

    const int qbase = blockIdx.x * (BLK * QPT) + threadIdx.x;

    float qx[QPT], qy[QPT], qz[QPT];
#pragma unroll
    for (int k = 0; k < QPT; ++k) {
        const int idx = qbase + k * BLK;
        if (idx < nQ) {
            const float* q = Q + ((size_t)b * nQ + idx) * 3;
            qx[k] = q[0]; qy[k] = q[1]; qz[k] = q[2];
        } else {
            qx[k] = 0.f; qy[k] = 0.f; qz[k] = 0.f;
        }
    }

    float acc[QPT];
#pragma unroll
    for (int k = 0; k < QPT; ++k) acc[k] = FLT_MAX;

    const float4* __restrict__ Tb = T + (size_t)b * nT;
    const int span = nT >> lc;      // 8192 >> lc : multiple of 8
    const int j0 = chunk * span;

    const float4* cur = Tb + j0;
    const int ngroups = span >> 3;  // 8 targets per group

    for (int g = 0; g < ngroups; ++g) {
        f32x16 A, Bv;
        // 2 x 64B scalar loads: 8 transformed targets into 32 SGPRs.
        asm volatile("s_load_dwordx16 %0, %2, 0\n\t"
                     "s_load_dwordx16 %1, %2, 64"
                     : "=&s"(A), "=&s"(Bv) : "s"(cur));
        // SMEM completes out-of-order -> only lgkmcnt(0) is safe. Tie the
        // loaded values through the wait so consumers can't hoist above it.
        asm volatile("s_waitcnt lgkmcnt(0)" : "+s"(A), "+s"(Bv));

#pragma unroll
        for (int h = 0; h < 2; ++h) {   // A then Bv
            const f32x16& V = h ? Bv : A;
#pragma unroll
            for (int t = 0; t < 2; ++t) {   // 2 target-pairs per f32x16
                const float px0 = V[8*t+0], py0 = V[8*t+1], pz0 = V[8*t+2], pw0 = V[8*t+3];
                const float px1 = V[8*t+4], py1 = V[8*t+5], pz1 = V[8*t+6], pw1 = V[8*t+7];
#pragma unroll
                for (int k = 0; k < QPT; ++k) {
                    const float d0 = fmaf(qx[k], px0, fmaf(qy[k], py0, fmaf(qz[k], pz0, pw0)));
                    const float d1 = fmaf(qx[k], px1, fmaf(qy[k], py1, fmaf(qz[k], pz1, pw1)));
                    acc[k] = fminf(fminf(d0, d1), acc[k]);   // -> v_min3_f32
                }
            }
        }
        cur += 8;
    }

    // Generic tail (span always multiple of 8 here; kept for safety).
    for (int j = (ngroups << 3); j < span; ++j) {
        const float4 p = Tb[j0 + j];
#pragma unroll
        for (int k = 0; k < QPT; ++k)
            acc[k] = fminf(acc[k], fmaf(qx[k], p.x, fmaf(qy[k], p.y, fmaf(qz[k], p.z, p.w))));
    }

#pragma unroll
    for (int k = 0; k < QPT; ++k) {
        const int idx = qbase + k * BLK;
        if (idx < nQ) {
            const float qq = fmaf(qx[k], qx[k], fmaf(qy[k], qy[k], qz[k] * qz[k]));
            const float dist = fmaf(2.f, acc[k], qq);
            const size_t off = (dir == 0) ? ((size_t)b * N + idx)
                                          : ((size_t)B * N + (size_t)b * M + idx);
            partial[(size_t)chunk * outn + off] = dist;
        }
    }
}

// Pass 3: min over chunks.
__global__ __launch_bounds__(BLK) void reduce_kernel(
    const float* __restrict__ partial, float* __restrict__ out, int outn, int chunks)
{
    const int k = blockIdx.x * BLK + threadIdx.x;
    if (k < outn) {
        float m = partial[k];
        for (int c = 1; c < chunks; ++c)
            m = fminf(m, partial[(size_t)c * outn + k]);
        out[k] = m;
    }
}

// Fallback (only if ws_size is too small).
__global__ __launch_bounds__(BLK) void chamfer_fallback(
    const float* __restrict__ xyz1, const float* __restrict__ xyz2,
    float* __restrict__ out, int B, int N, int M)
{
    const int dir = blockIdx.z;
    const int b   = blockIdx.y;
    const float* Q = (dir == 0) ? xyz1 : xyz2;
    const float* T = (dir == 0) ? xyz2 : xyz1;
    const int nQ = (dir == 0) ? N : M;
    const int nT = (dir == 0) ? M : N;
    const int i = blockIdx.x * BLK + threadIdx.x;

    float x0 = 0.f, x1 = 0.f, x2 = 0.f;
    if (i < nQ) {
        const float* q = Q + ((size_t)b * nQ + i) * 3;
        x0 = q[0]; x1 = q[1]; x2 = q[2];
    }
    float best = FLT_MAX;
    for (int jj = 0; jj < nT; ++jj) {
        const float* t = T + ((size_t)b * nT + jj) * 3;
        float t0 = t[0] - x0, t1 = t[1] - x1, t2 = t[2] - x2;
        best = fminf(best, fmaf(t0, t0, fmaf(t1, t1, t2 * t2)));
    }
    if (i < nQ) {
        const size_t off = (dir == 0) ? ((size_t)b * N + i)
                                      : ((size_t)B * N + (size_t)b * M + i);
        out[off] = best;
    }
}

extern "C" void kernel_launch(void* const* d_in, const int* in_sizes, int n_in,
                              void* d_out, int out_size, void* d_ws, size_t ws_size,
                              hipStream_t stream) {
    const float* xyz1 = (const float*)d_in[0];
    const float* xyz2 = (const float*)d_in[1];
    float* out = (float*)d_out;

    const int B = 8, N = 8192, M = 8192;
    const int n1 = B * N, n2 = B * M;
    const int outn = B * (N + M);

    const size_t t1_bytes = (size_t)n1 * sizeof(float4);
    const size_t t2_bytes = (size_t)n2 * sizeof(float4);

    int lc = -1;
    for (int try_lc = 5; try_lc >= 0; --try_lc) {   // chunks = 32..1
        const size_t part = ((size_t)1 << try_lc) * (size_t)outn * sizeof(float);
        if (t1_bytes + t2_bytes + part <= ws_size) { lc = try_lc; break; }
    }

    if (lc >= 0) {
        const int chunks = 1 << lc;
        float4* t1 = (float4*)d_ws;
        float4* t2 = (float4*)((char*)d_ws + t1_bytes);
        float* partial = (float*)((char*)d_ws + t1_bytes + t2_bytes);

        const int nmax_pts = (n1 > n2) ? n1 : n2;
        transform_kernel<<<(nmax_pts + BLK - 1) / BLK, BLK, 0, stream>>>(
            xyz1, xyz2, t1, t2, n1, n2);

        const int nmax = (N > M) ? N : M;
        dim3 grid((unsigned)((nmax + BLK * QPT - 1) / (BLK * QPT)), (unsigned)B,
                  (unsigned)(2 * chunks));
        chamfer_main<<<grid, dim3(BLK, 1, 1), 0, stream>>>(
            xyz1, xyz2, t1, t2, partial, B, N, M, outn, lc);

        reduce_kernel<<<(outn + BLK - 1) / BLK, BLK, 0, stream>>>(partial, out, outn, chunks);
    } else {
        const int nmax = (N > M) ? N : M;
        dim3 grid((unsigned)((nmax + BLK - 1) / BLK), (unsigned)B, 2);
        chamfer_fallback<<<grid, dim3(BLK, 1, 1), 0, stream>>>(xyz1, xyz2, out, B, N, M);
    }
}

// Round 9
// 101.108 us; speedup vs baseline: 4.6131x; 1.2137x over previous
//
#include <hip/hip_runtime.h>
#include <float.h>

#define BLK 256
#define QPT 8   // query points per thread

typedef float f32x2  __attribute__((ext_vector_type(2)));
typedef float f32x16 __attribute__((ext_vector_type(16)));

// Elementwise packed helpers — compiler-generated <2 x float> ops select
// v_pk_fma_f32 / v_pk_min_f32 on gfx950 with guaranteed-correct encodings
// (no hand-written VOP3P op_sel assumptions — the r6/r7/r8 failure family).
#if __has_builtin(__builtin_elementwise_fma)
static __device__ __forceinline__ f32x2 efma(f32x2 a, f32x2 b, f32x2 c) {
    return __builtin_elementwise_fma(a, b, c);
}
#else
static __device__ __forceinline__ f32x2 efma(f32x2 a, f32x2 b, f32x2 c) {
    f32x2 r; r.x = fmaf(a.x, b.x, c.x); r.y = fmaf(a.y, b.y, c.y); return r;
}
#endif
#if __has_builtin(__builtin_elementwise_min)
static __device__ __forceinline__ f32x2 emin(f32x2 a, f32x2 b) {
    return __builtin_elementwise_min(a, b);
}
#else
static __device__ __forceinline__ f32x2 emin(f32x2 a, f32x2 b) {
    f32x2 r; r.x = fminf(a.x, b.x); r.y = fminf(a.y, b.y); return r;
}
#endif

// Pass 1: pair-transposed transform. Per GROUP of 4 targets t0..t3, emit 16 floats:
// V[0:1]=(-t0x,-t1x) V[2:3]=(-t0y,-t1y) V[4:5]=(-t0z,-t1z)
// V[6:7]=(-t2x,-t3x) V[8:9]=(-t2y,-t3y) V[10:11]=(-t2z,-t3z)
// V[12:13]=(.5|t0|^2,.5|t1|^2) V[14:15]=(.5|t2|^2,.5|t3|^2)
__global__ __launch_bounds__(BLK) void transform_kernel(
    const float* __restrict__ xyz1, const float* __restrict__ xyz2,
    float* __restrict__ o1, float* __restrict__ o2, int g1, int g2)
{
    const int i = blockIdx.x * BLK + threadIdx.x;
    auto doGroup = [](const float* __restrict__ in, float* __restrict__ out, int gi) {
        const float4* in4 = reinterpret_cast<const float4*>(in + 12 * (size_t)gi);  // 48B: 16B-aligned
        const float4 a = in4[0], b = in4[1], c = in4[2];
        // t0=(a.x,a.y,a.z) t1=(a.w,b.x,b.y) t2=(b.z,b.w,c.x) t3=(c.y,c.z,c.w)
        const float w0 = 0.5f * fmaf(a.x, a.x, fmaf(a.y, a.y, a.z * a.z));
        const float w1 = 0.5f * fmaf(a.w, a.w, fmaf(b.x, b.x, b.y * b.y));
        const float w2 = 0.5f * fmaf(b.z, b.z, fmaf(b.w, b.w, c.x * c.x));
        const float w3 = 0.5f * fmaf(c.y, c.y, fmaf(c.z, c.z, c.w * c.w));
        float4* out4 = reinterpret_cast<float4*>(out + 16 * (size_t)gi);
        out4[0] = make_float4(-a.x, -a.w, -a.y, -b.x);
        out4[1] = make_float4(-a.z, -b.y, -b.z, -c.y);
        out4[2] = make_float4(-b.w, -c.z, -c.x, -c.w);
        out4[3] = make_float4( w0,   w1,   w2,   w3);
    };
    if (i < g1) doGroup(xyz1, o1, i);
    if (i < g2) doGroup(xyz2, o2, i);
}

// Pass 2: SMEM-fed packed-FMA main loop. ONE asm block issues both
// s_load_dwordx16 and the lgkmcnt(0) wait (outputs defined only at asm end —
// no hazard window). All math is compiler-generated packed f32.
__global__ __launch_bounds__(BLK) void chamfer_main(
    const float* __restrict__ xyz1, const float* __restrict__ xyz2,
    const float* __restrict__ t1, const float* __restrict__ t2,
    float* __restrict__ partial, int B, int N, int M, int outn, int lc)
{
    const int chunks = 1 << lc;
    const int z     = blockIdx.z;
    const int dir   = z >> lc;
    const int chunk = z & (chunks - 1);
    const int b     = blockIdx.y;

    const float* Q = (dir == 0) ? xyz1 : xyz2;
    const float* T = (dir == 0) ? t2   : t1;
    const int nQ = (dir == 0) ? N : M;
    const int nT = (dir == 0) ? M : N;

    const int qbase = blockIdx.x * (BLK * QPT) + threadIdx.x;

    f32x2 qx2[QPT], qy2[QPT], qz2[QPT], acc2[QPT];
#pragma unroll
    for (int k = 0; k < QPT; ++k) {
        const int idx = qbase + k * BLK;
        float x = 0.f, y = 0.f, zz = 0.f;
        if (idx < nQ) {
            const float* q = Q + ((size_t)b * nQ + idx) * 3;
            x = q[0]; y = q[1]; zz = q[2];
        }
        qx2[k] = (f32x2){x, x};
        qy2[k] = (f32x2){y, y};
        qz2[k] = (f32x2){zz, zz};
        acc2[k] = (f32x2){FLT_MAX, FLT_MAX};
    }

    const int span = nT >> lc;                 // multiple of 8
    const int ngroups = span >> 2;             // groups of 4 targets (even)
    const f32x16* gp = reinterpret_cast<const f32x16*>(T)
                     + (((size_t)b * nT + (size_t)chunk * span) >> 2);

    // Per group of 4 targets, per query: 6 pk_fma + 2 pk_min = 2.0 instr/pair.
    auto COMPUTE = [&](const f32x16& V) {
        const f32x2 X0 = {V[0],  V[1]},  Y0 = {V[2],  V[3]},  Z0 = {V[4],  V[5]};
        const f32x2 X1 = {V[6],  V[7]},  Y1 = {V[8],  V[9]},  Z1 = {V[10], V[11]};
        const f32x2 W0 = {V[12], V[13]}, W1 = {V[14], V[15]};
#pragma unroll
        for (int k = 0; k < QPT; ++k) {
            f32x2 d0 = efma(qz2[k], Z0, W0);
            d0 = efma(qy2[k], Y0, d0);
            d0 = efma(qx2[k], X0, d0);
            f32x2 d1 = efma(qz2[k], Z1, W1);
            d1 = efma(qy2[k], Y1, d1);
            d1 = efma(qx2[k], X1, d1);
            acc2[k] = emin(acc2[k], emin(d0, d1));
        }
    };

    for (int g = 0; g < ngroups; g += 2) {
        f32x16 A, Bv;
        // Load 2 groups (8 targets, 128 B) and wait in ONE asm block.
        asm volatile("s_load_dwordx16 %0, %2, 0\n\t"
                     "s_load_dwordx16 %1, %2, 64\n\t"
                     "s_waitcnt lgkmcnt(0)"
                     : "=&s"(A), "=&s"(Bv)
                     : "s"(gp));
        COMPUTE(A);
        COMPUTE(Bv);
        gp += 2;
    }

#pragma unroll
    for (int k = 0; k < QPT; ++k) {
        const int idx = qbase + k * BLK;
        if (idx < nQ) {
            const float x = qx2[k].x, y = qy2[k].x, zz = qz2[k].x;
            const float qq = fmaf(x, x, fmaf(y, y, zz * zz));
            const float acc = fminf(acc2[k].x, acc2[k].y);
            const float dist = fmaf(2.f, acc, qq);
            const size_t off = (dir == 0) ? ((size_t)b * N + idx)
                                          : ((size_t)B * N + (size_t)b * M + idx);
            partial[(size_t)chunk * outn + off] = dist;
        }
    }
}

// Pass 3: min over chunks.
__global__ __launch_bounds__(BLK) void reduce_kernel(
    const float* __restrict__ partial, float* __restrict__ out, int outn, int chunks)
{
    const int k = blockIdx.x * BLK + threadIdx.x;
    if (k < outn) {
        float m = partial[k];
        for (int c = 1; c < chunks; ++c)
            m = fminf(m, partial[(size_t)c * outn + k]);
        out[k] = m;
    }
}

// Fallback (only if ws_size is too small).
__global__ __launch_bounds__(BLK) void chamfer_fallback(
    const float* __restrict__ xyz1, const float* __restrict__ xyz2,
    float* __restrict__ out, int B, int N, int M)
{
    const int dir = blockIdx.z;
    const int b   = blockIdx.y;
    const float* Q = (dir == 0) ? xyz1 : xyz2;
    const float* T = (dir == 0) ? xyz2 : xyz1;
    const int nQ = (dir == 0) ? N : M;
    const int nT = (dir == 0) ? M : N;
    const int i = blockIdx.x * BLK + threadIdx.x;

    float x0 = 0.f, x1 = 0.f, x2 = 0.f;
    if (i < nQ) {
        const float* q = Q + ((size_t)b * nQ + i) * 3;
        x0 = q[0]; x1 = q[1]; x2 = q[2];
    }
    float best = FLT_MAX;
    for (int jj = 0; jj < nT; ++jj) {
        const float* t = T + ((size_t)b * nT + jj) * 3;
        float t0 = t[0] - x0, t1 = t[1] - x1, t2 = t[2] - x2;
        best = fminf(best, fmaf(t0, t0, fmaf(t1, t1, t2 * t2)));
    }
    if (i < nQ) {
        const size_t off = (dir == 0) ? ((size_t)b * N + i)
                                      : ((size_t)B * N + (size_t)b * M + i);
        out[off] = best;
    }
}

extern "C" void kernel_launch(void* const* d_in, const int* in_sizes, int n_in,
                              void* d_out, int out_size, void* d_ws, size_t ws_size,
                              hipStream_t stream) {
    const float* xyz1 = (const float*)d_in[0];
    const float* xyz2 = (const float*)d_in[1];
    float* out = (float*)d_out;

    const int B = 8, N = 8192, M = 8192;
    const int n1 = B * N, n2 = B * M;
    const int outn = B * (N + M);
    const int g1 = n1 / 4, g2 = n2 / 4;

    const size_t t1_bytes = (size_t)g1 * 64;   // 16 floats per 4 targets
    const size_t t2_bytes = (size_t)g2 * 64;

    int lc = -1;
    for (int try_lc = 5; try_lc >= 0; --try_lc) {   // chunks = 32..1
        const size_t part = ((size_t)1 << try_lc) * (size_t)outn * sizeof(float);
        if (t1_bytes + t2_bytes + part <= ws_size) { lc = try_lc; break; }
    }

    if (lc >= 0) {
        const int chunks = 1 << lc;
        float* t1 = (float*)d_ws;
        float* t2 = (float*)((char*)d_ws + t1_bytes);
        float* partial = (float*)((char*)d_ws + t1_bytes + t2_bytes);

        const int gmax = (g1 > g2) ? g1 : g2;
        transform_kernel<<<(gmax + BLK - 1) / BLK, BLK, 0, stream>>>(
            xyz1, xyz2, t1, t2, g1, g2);

        const int nmax = (N > M) ? N : M;
        dim3 grid((unsigned)((nmax + BLK * QPT - 1) / (BLK * QPT)), (unsigned)B,
                  (unsigned)(2 * chunks));
        chamfer_main<<<grid, dim3(BLK, 1, 1), 0, stream>>>(
            xyz1, xyz2, t1, t2, partial, B, N, M, outn, lc);

        reduce_kernel<<<(outn + BLK - 1) / BLK, BLK, 0, stream>>>(partial, out, outn, chunks);
    } else {
        const int nmax = (N > M) ? N : M;
        dim3 grid((unsigned)((nmax + BLK - 1) / BLK), (unsigned)B, 2);
        chamfer_fallback<<<grid, dim3(BLK, 1, 1), 0, stream>>>(xyz1, xyz2, out, B, N, M);
    }
}

// Round 10
// 91.701 us; speedup vs baseline: 5.0863x; 1.1026x over previous
//
#include <hip/hip_runtime.h>
#include <float.h>

#define BLK 256
#define QPT 8      // query points per thread
#define LC  5      // log2 chunk count
#define CHUNKS (1 << LC)
#define SPAN 256   // 8192 >> LC targets per chunk (= BLK: 1 float4/thread stage)

typedef float f32x2 __attribute__((ext_vector_type(2)));

#if __has_builtin(__builtin_elementwise_fma)
static __device__ __forceinline__ f32x2 efma(f32x2 a, f32x2 b, f32x2 c) {
    return __builtin_elementwise_fma(a, b, c);
}
#else
static __device__ __forceinline__ f32x2 efma(f32x2 a, f32x2 b, f32x2 c) {
    f32x2 r; r.x = fmaf(a.x, b.x, c.x); r.y = fmaf(a.y, b.y, c.y); return r;
}
#endif
#if __has_builtin(__builtin_elementwise_min)
static __device__ __forceinline__ f32x2 emin(f32x2 a, f32x2 b) {
    return __builtin_elementwise_min(a, b);
}
#else
static __device__ __forceinline__ f32x2 emin(f32x2 a, f32x2 b) {
    f32x2 r; r.x = fminf(a.x, b.x); r.y = fminf(a.y, b.y); return r;
}
#endif

// Init: out <- +INF (as int bits) so atomicMin-as-int accumulates float mins.
__global__ __launch_bounds__(BLK) void init_out(int* __restrict__ outI, int n) {
    const int i = blockIdx.x * BLK + threadIdx.x;
    if (i < n) outI[i] = 0x7F800000;  // +inf
}

// Pass 1 (unchanged, proven): pair-transposed transform. Per GROUP of 4
// targets t0..t3, emit 16 floats = 4 float4s:
// f4#0=(-t0x,-t1x,-t0y,-t1y) f4#1=(-t0z,-t1z,-t2x,-t3x)
// f4#2=(-t2y,-t3y,-t2z,-t3z) f4#3=(.5|t0|²,.5|t1|²,.5|t2|²,.5|t3|²)
__global__ __launch_bounds__(BLK) void transform_kernel(
    const float* __restrict__ xyz1, const float* __restrict__ xyz2,
    float* __restrict__ o1, float* __restrict__ o2, int g1, int g2)
{
    const int i = blockIdx.x * BLK + threadIdx.x;
    auto doGroup = [](const float* __restrict__ in, float* __restrict__ out, int gi) {
        const float4* in4 = reinterpret_cast<const float4*>(in + 12 * (size_t)gi);
        const float4 a = in4[0], b = in4[1], c = in4[2];
        // t0=(a.x,a.y,a.z) t1=(a.w,b.x,b.y) t2=(b.z,b.w,c.x) t3=(c.y,c.z,c.w)
        const float w0 = 0.5f * fmaf(a.x, a.x, fmaf(a.y, a.y, a.z * a.z));
        const float w1 = 0.5f * fmaf(a.w, a.w, fmaf(b.x, b.x, b.y * b.y));
        const float w2 = 0.5f * fmaf(b.z, b.z, fmaf(b.w, b.w, c.x * c.x));
        const float w3 = 0.5f * fmaf(c.y, c.y, fmaf(c.z, c.z, c.w * c.w));
        float4* out4 = reinterpret_cast<float4*>(out + 16 * (size_t)gi);
        out4[0] = make_float4(-a.x, -a.w, -a.y, -b.x);
        out4[1] = make_float4(-a.z, -b.y, -b.z, -c.y);
        out4[2] = make_float4(-b.w, -c.z, -c.x, -c.w);
        out4[3] = make_float4( w0,   w1,   w2,   w3);
    };
    if (i < g1) doGroup(xyz1, o1, i);
    if (i < g2) doGroup(xyz2, o2, i);
}

// Pass 2: LDS-broadcast-fed packed-FMA main loop. Stage the chunk (4 KB)
// into LDS once (coalesced float4/thread), then all target reads are
// wave-uniform LDS loads (same-address broadcast, conflict-free, in-order
// -> counted lgkmcnt, compiler-pipelined). Epilogue: atomicMin-as-int.
__global__ __launch_bounds__(BLK) void chamfer_main(
    const float* __restrict__ xyz1, const float* __restrict__ xyz2,
    const float* __restrict__ t1, const float* __restrict__ t2,
    int* __restrict__ outI, int B, int N, int M)
{
    const int z     = blockIdx.z;          // [0, 2*CHUNKS)
    const int dir   = z >> LC;
    const int chunk = z & (CHUNKS - 1);
    const int b     = blockIdx.y;

    const float* Q = (dir == 0) ? xyz1 : xyz2;
    const float* T = (dir == 0) ? t2   : t1;
    const int nQ = (dir == 0) ? N : M;
    const int nT = (dir == 0) ? M : N;

    __shared__ float4 lds[SPAN];           // span targets * 16 B

    const int span = nT >> LC;             // == SPAN (N=M=8192)
    // Transformed layout: 4 float4 per 4 targets -> float4 index == target index.
    const float4* Tf4 = reinterpret_cast<const float4*>(T);
    const int tbase = b * nT + chunk * span;
    for (int t = threadIdx.x; t < span; t += BLK)
        lds[t] = Tf4[tbase + t];
    __syncthreads();

    const int qbase = blockIdx.x * (BLK * QPT) + threadIdx.x;

    f32x2 qx2[QPT], qy2[QPT], qz2[QPT], acc2[QPT];
#pragma unroll
    for (int k = 0; k < QPT; ++k) {
        const int idx = qbase + k * BLK;
        float x = 0.f, y = 0.f, zz = 0.f;
        if (idx < nQ) {
            const float* q = Q + ((size_t)b * nQ + idx) * 3;
            x = q[0]; y = q[1]; zz = q[2];
        }
        qx2[k] = (f32x2){x, x};
        qy2[k] = (f32x2){y, y};
        qz2[k] = (f32x2){zz, zz};
        acc2[k] = (f32x2){FLT_MAX, FLT_MAX};
    }

    // Per group of 4 targets, per query: 6 pk_fma + 2 pk_min = 2.0 instr/pair.
    auto COMPUTE = [&](float4 v0, float4 v1, float4 v2, float4 v3) {
        const f32x2 X0 = {v0.x, v0.y}, Y0 = {v0.z, v0.w};
        const f32x2 Z0 = {v1.x, v1.y}, X1 = {v1.z, v1.w};
        const f32x2 Y1 = {v2.x, v2.y}, Z1 = {v2.z, v2.w};
        const f32x2 W0 = {v3.x, v3.y}, W1 = {v3.z, v3.w};
#pragma unroll
        for (int k = 0; k < QPT; ++k) {
            f32x2 d0 = efma(qz2[k], Z0, W0);
            d0 = efma(qy2[k], Y0, d0);
            d0 = efma(qx2[k], X0, d0);
            f32x2 d1 = efma(qz2[k], Z1, W1);
            d1 = efma(qy2[k], Y1, d1);
            d1 = efma(qx2[k], X1, d1);
            acc2[k] = emin(acc2[k], emin(d0, d1));
        }
    };

    const int ngroups = span >> 2;         // groups of 4 targets (64, even)
    for (int g = 0; g < ngroups; g += 2) {
        // Batch both groups' 8 uniform ds_read_b128, then compute.
        const float4 v0 = lds[4*g + 0], v1 = lds[4*g + 1];
        const float4 v2 = lds[4*g + 2], v3 = lds[4*g + 3];
        const float4 u0 = lds[4*g + 4], u1 = lds[4*g + 5];
        const float4 u2 = lds[4*g + 6], u3 = lds[4*g + 7];
        COMPUTE(v0, v1, v2, v3);
        COMPUTE(u0, u1, u2, u3);
    }

#pragma unroll
    for (int k = 0; k < QPT; ++k) {
        const int idx = qbase + k * BLK;
        if (idx < nQ) {
            const float x = qx2[k].x, y = qy2[k].x, zz = qz2[k].x;
            const float qq = fmaf(x, x, fmaf(y, y, zz * zz));
            const float acc = fminf(acc2[k].x, acc2[k].y);
            const float dist = fmaf(2.f, acc, qq);   // >= ~0 -> int order == float order
            const size_t off = (dir == 0) ? ((size_t)b * N + idx)
                                          : ((size_t)B * N + (size_t)b * M + idx);
            atomicMin(outI + off, __float_as_int(dist));
        }
    }
}

// Fallback (only if ws_size is too small for the 2 MB transform buffers).
__global__ __launch_bounds__(BLK) void chamfer_fallback(
    const float* __restrict__ xyz1, const float* __restrict__ xyz2,
    float* __restrict__ out, int B, int N, int M)
{
    const int dir = blockIdx.z;
    const int b   = blockIdx.y;
    const float* Q = (dir == 0) ? xyz1 : xyz2;
    const float* T = (dir == 0) ? xyz2 : xyz1;
    const int nQ = (dir == 0) ? N : M;
    const int nT = (dir == 0) ? M : N;
    const int i = blockIdx.x * BLK + threadIdx.x;

    float x0 = 0.f, x1 = 0.f, x2 = 0.f;
    if (i < nQ) {
        const float* q = Q + ((size_t)b * nQ + i) * 3;
        x0 = q[0]; x1 = q[1]; x2 = q[2];
    }
    float best = FLT_MAX;
    for (int jj = 0; jj < nT; ++jj) {
        const float* t = T + ((size_t)b * nT + jj) * 3;
        float t0 = t[0] - x0, t1 = t[1] - x1, t2 = t[2] - x2;
        best = fminf(best, fmaf(t0, t0, fmaf(t1, t1, t2 * t2)));
    }
    if (i < nQ) {
        const size_t off = (dir == 0) ? ((size_t)b * N + i)
                                      : ((size_t)B * N + (size_t)b * M + i);
        out[off] = best;
    }
}

extern "C" void kernel_launch(void* const* d_in, const int* in_sizes, int n_in,
                              void* d_out, int out_size, void* d_ws, size_t ws_size,
                              hipStream_t stream) {
    const float* xyz1 = (const float*)d_in[0];
    const float* xyz2 = (const float*)d_in[1];

    const int B = 8, N = 8192, M = 8192;
    const int n1 = B * N, n2 = B * M;
    const int outn = B * (N + M);
    const int g1 = n1 / 4, g2 = n2 / 4;

    const size_t t1_bytes = (size_t)g1 * 64;   // 16 floats per 4 targets (1 MB)
    const size_t t2_bytes = (size_t)g2 * 64;

    if (ws_size >= t1_bytes + t2_bytes) {
        float* t1 = (float*)d_ws;
        float* t2 = (float*)((char*)d_ws + t1_bytes);
        int* outI = (int*)d_out;

        init_out<<<(outn + BLK - 1) / BLK, BLK, 0, stream>>>(outI, outn);

        const int gmax = (g1 > g2) ? g1 : g2;
        transform_kernel<<<(gmax + BLK - 1) / BLK, BLK, 0, stream>>>(
            xyz1, xyz2, t1, t2, g1, g2);

        const int nmax = (N > M) ? N : M;
        dim3 grid((unsigned)((nmax + BLK * QPT - 1) / (BLK * QPT)), (unsigned)B,
                  (unsigned)(2 * CHUNKS));
        chamfer_main<<<grid, dim3(BLK, 1, 1), 0, stream>>>(
            xyz1, xyz2, t1, t2, outI, B, N, M);
    } else {
        const int nmax = (N > M) ? N : M;
        dim3 grid((unsigned)((nmax + BLK - 1) / BLK), (unsigned)B, 2);
        chamfer_fallback<<<grid, dim3(BLK, 1, 1), 0, stream>>>(
            xyz1, xyz2, (float*)d_out, B, N, M);
    }
}

// Round 11
// 88.088 us; speedup vs baseline: 5.2949x; 1.0410x over previous
//
#include <hip/hip_runtime.h>
#include <float.h>

#define BLK 256
#define QPT 16     // query points per thread
#define LC  5      // log2 chunk count
#define CHUNKS (1 << LC)
#define SPAN 256   // 8192 >> LC targets per chunk (= BLK: 1 float4/thread stage)

typedef float f32x2 __attribute__((ext_vector_type(2)));

#if __has_builtin(__builtin_elementwise_fma)
static __device__ __forceinline__ f32x2 efma(f32x2 a, f32x2 b, f32x2 c) {
    return __builtin_elementwise_fma(a, b, c);
}
#else
static __device__ __forceinline__ f32x2 efma(f32x2 a, f32x2 b, f32x2 c) {
    f32x2 r; r.x = fmaf(a.x, b.x, c.x); r.y = fmaf(a.y, b.y, c.y); return r;
}
#endif

// Init: out <- +INF (as int bits) so atomicMin-as-int accumulates float mins.
__global__ __launch_bounds__(BLK) void init_out(int* __restrict__ outI, int n) {
    const int i = blockIdx.x * BLK + threadIdx.x;
    if (i < n) outI[i] = 0x7F800000;  // +inf
}

// Pass 1 (proven): pair-transposed transform. Per GROUP of 4 targets t0..t3:
// f4#0=(-t0x,-t1x,-t0y,-t1y) f4#1=(-t0z,-t1z,-t2x,-t3x)
// f4#2=(-t2y,-t3y,-t2z,-t3z) f4#3=(.5|t0|²,.5|t1|²,.5|t2|²,.5|t3|²)
__global__ __launch_bounds__(BLK) void transform_kernel(
    const float* __restrict__ xyz1, const float* __restrict__ xyz2,
    float* __restrict__ o1, float* __restrict__ o2, int g1, int g2)
{
    const int i = blockIdx.x * BLK + threadIdx.x;
    auto doGroup = [](const float* __restrict__ in, float* __restrict__ out, int gi) {
        const float4* in4 = reinterpret_cast<const float4*>(in + 12 * (size_t)gi);
        const float4 a = in4[0], b = in4[1], c = in4[2];
        const float w0 = 0.5f * fmaf(a.x, a.x, fmaf(a.y, a.y, a.z * a.z));
        const float w1 = 0.5f * fmaf(a.w, a.w, fmaf(b.x, b.x, b.y * b.y));
        const float w2 = 0.5f * fmaf(b.z, b.z, fmaf(b.w, b.w, c.x * c.x));
        const float w3 = 0.5f * fmaf(c.y, c.y, fmaf(c.z, c.z, c.w * c.w));
        float4* out4 = reinterpret_cast<float4*>(out + 16 * (size_t)gi);
        out4[0] = make_float4(-a.x, -a.w, -a.y, -b.x);
        out4[1] = make_float4(-a.z, -b.y, -b.z, -c.y);
        out4[2] = make_float4(-b.w, -c.z, -c.x, -c.w);
        out4[3] = make_float4( w0,   w1,   w2,   w3);
    };
    if (i < g1) doGroup(xyz1, o1, i);
    if (i < g2) doGroup(xyz2, o2, i);
}

// Pass 2: LDS-broadcast feed (proven) + packed FMA + v_min3_f32 accumulation
// (r5-proven asm). Per 4 targets per query: 6 pk_fma (24 cyc) + 2 min3 (4 cyc)
// = 7 SIMD-cyc per pair-lane, vs r10's 8. QPT=16 halves LDS-pipe demand.
__global__ __launch_bounds__(BLK) void chamfer_main(
    const float* __restrict__ xyz1, const float* __restrict__ xyz2,
    const float* __restrict__ t1, const float* __restrict__ t2,
    int* __restrict__ outI, int B, int N, int M)
{
    const int z     = blockIdx.z;          // [0, 2*CHUNKS)
    const int dir   = z >> LC;
    const int chunk = z & (CHUNKS - 1);
    const int b     = blockIdx.y;

    const float* Q = (dir == 0) ? xyz1 : xyz2;
    const float* T = (dir == 0) ? t2   : t1;
    const int nQ = (dir == 0) ? N : M;
    const int nT = (dir == 0) ? M : N;

    __shared__ float4 lds[SPAN];

    const int span = nT >> LC;             // == SPAN
    const float4* Tf4 = reinterpret_cast<const float4*>(T);
    const int tbase = b * nT + chunk * span;
    for (int t = threadIdx.x; t < span; t += BLK)
        lds[t] = Tf4[tbase + t];
    __syncthreads();

    const int qbase = blockIdx.x * (BLK * QPT) + threadIdx.x;

    f32x2 qx2[QPT], qy2[QPT], qz2[QPT];
    float acc[QPT];
#pragma unroll
    for (int k = 0; k < QPT; ++k) {
        const int idx = qbase + k * BLK;
        float x = 0.f, y = 0.f, zz = 0.f;
        if (idx < nQ) {
            const float* q = Q + ((size_t)b * nQ + idx) * 3;
            x = q[0]; y = q[1]; zz = q[2];
        }
        qx2[k] = (f32x2){x, x};
        qy2[k] = (f32x2){y, y};
        qz2[k] = (f32x2){zz, zz};
        acc[k] = FLT_MAX;
    }

    auto COMPUTE = [&](float4 v0, float4 v1, float4 v2, float4 v3) {
        const f32x2 X0 = {v0.x, v0.y}, Y0 = {v0.z, v0.w};
        const f32x2 Z0 = {v1.x, v1.y}, X1 = {v1.z, v1.w};
        const f32x2 Y1 = {v2.x, v2.y}, Z1 = {v2.z, v2.w};
        const f32x2 W0 = {v3.x, v3.y}, W1 = {v3.z, v3.w};
#pragma unroll
        for (int k = 0; k < QPT; ++k) {
            f32x2 d0 = efma(qz2[k], Z0, W0);
            d0 = efma(qy2[k], Y0, d0);
            d0 = efma(qx2[k], X0, d0);
            f32x2 d1 = efma(qz2[k], Z1, W1);
            d1 = efma(qy2[k], Y1, d1);
            d1 = efma(qx2[k], X1, d1);
            // r5-proven v_min3_f32: two ops fold 4 candidates into acc.
            asm("v_min3_f32 %0, %1, %2, %3"
                : "=v"(acc[k]) : "v"(d1.x), "v"(d1.y), "0"(acc[k]));
            asm("v_min3_f32 %0, %1, %2, %3"
                : "=v"(acc[k]) : "v"(d0.x), "v"(d0.y), "0"(acc[k]));
        }
    };

    const int ngroups = span >> 2;         // 64 groups of 4 targets
    for (int g = 0; g < ngroups; g += 2) {
        const float4 v0 = lds[4*g + 0], v1 = lds[4*g + 1];
        const float4 v2 = lds[4*g + 2], v3 = lds[4*g + 3];
        const float4 u0 = lds[4*g + 4], u1 = lds[4*g + 5];
        const float4 u2 = lds[4*g + 6], u3 = lds[4*g + 7];
        COMPUTE(v0, v1, v2, v3);
        COMPUTE(u0, u1, u2, u3);
    }

#pragma unroll
    for (int k = 0; k < QPT; ++k) {
        const int idx = qbase + k * BLK;
        if (idx < nQ) {
            const float x = qx2[k].x, y = qy2[k].x, zz = qz2[k].x;
            const float qq = fmaf(x, x, fmaf(y, y, zz * zz));
            const float dist = fmaf(2.f, acc[k], qq);
            const size_t off = (dir == 0) ? ((size_t)b * N + idx)
                                          : ((size_t)B * N + (size_t)b * M + idx);
            atomicMin(outI + off, __float_as_int(dist));
        }
    }
}

// Fallback (only if ws_size is too small for the 2 MB transform buffers).
__global__ __launch_bounds__(BLK) void chamfer_fallback(
    const float* __restrict__ xyz1, const float* __restrict__ xyz2,
    float* __restrict__ out, int B, int N, int M)
{
    const int dir = blockIdx.z;
    const int b   = blockIdx.y;
    const float* Q = (dir == 0) ? xyz1 : xyz2;
    const float* T = (dir == 0) ? xyz2 : xyz1;
    const int nQ = (dir == 0) ? N : M;
    const int nT = (dir == 0) ? M : N;
    const int i = blockIdx.x * BLK + threadIdx.x;

    float x0 = 0.f, x1 = 0.f, x2 = 0.f;
    if (i < nQ) {
        const float* q = Q + ((size_t)b * nQ + i) * 3;
        x0 = q[0]; x1 = q[1]; x2 = q[2];
    }
    float best = FLT_MAX;
    for (int jj = 0; jj < nT; ++jj) {
        const float* t = T + ((size_t)b * nT + jj) * 3;
        float t0 = t[0] - x0, t1 = t[1] - x1, t2 = t[2] - x2;
        best = fminf(best, fmaf(t0, t0, fmaf(t1, t1, t2 * t2)));
    }
    if (i < nQ) {
        const size_t off = (dir == 0) ? ((size_t)b * N + i)
                                      : ((size_t)B * N + (size_t)b * M + i);
        out[off] = best;
    }
}

extern "C" void kernel_launch(void* const* d_in, const int* in_sizes, int n_in,
                              void* d_out, int out_size, void* d_ws, size_t ws_size,
                              hipStream_t stream) {
    const float* xyz1 = (const float*)d_in[0];
    const float* xyz2 = (const float*)d_in[1];

    const int B = 8, N = 8192, M = 8192;
    const int n1 = B * N, n2 = B * M;
    const int outn = B * (N + M);
    const int g1 = n1 / 4, g2 = n2 / 4;

    const size_t t1_bytes = (size_t)g1 * 64;
    const size_t t2_bytes = (size_t)g2 * 64;

    if (ws_size >= t1_bytes + t2_bytes) {
        float* t1 = (float*)d_ws;
        float* t2 = (float*)((char*)d_ws + t1_bytes);
        int* outI = (int*)d_out;

        init_out<<<(outn + BLK - 1) / BLK, BLK, 0, stream>>>(outI, outn);

        const int gmax = (g1 > g2) ? g1 : g2;
        transform_kernel<<<(gmax + BLK - 1) / BLK, BLK, 0, stream>>>(
            xyz1, xyz2, t1, t2, g1, g2);

        const int nmax = (N > M) ? N : M;
        dim3 grid((unsigned)((nmax + BLK * QPT - 1) / (BLK * QPT)), (unsigned)B,
                  (unsigned)(2 * CHUNKS));
        chamfer_main<<<grid, dim3(BLK, 1, 1), 0, stream>>>(
            xyz1, xyz2, t1, t2, outI, B, N, M);
    } else {
        const int nmax = (N > M) ? N : M;
        dim3 grid((unsigned)((nmax + BLK - 1) / BLK), (unsigned)B, 2);
        chamfer_fallback<<<grid, dim3(BLK, 1, 1), 0, stream>>>(
            xyz1, xyz2, (float*)d_out, B, N, M);
    }
}